// Round 22
// baseline (517.898 us; speedup 1.0000x reference)
//
#include <hip/hip_runtime.h>
#include <math.h>

#define NANCH 735
#define NCAND 26460     // 735*36
#define NCANDP 26624    // 13*2048
#define BBCLIP 4.135166556742356f
#define KF1 4864        // fc1 factored K: 2 images * (49*49=2401 padded to 2432)
#define KHALF 2432
#define MROW 768        // padded rows per image in roi-major tensors
#define MTOT 1536

typedef short bf16x8 __attribute__((ext_vector_type(8)));
typedef float f32x4 __attribute__((ext_vector_type(4)));

__device__ __forceinline__ unsigned short f2b(float f) {
  unsigned int u = __float_as_uint(f);
  unsigned int r = (u >> 16) & 1u;
  u += 0x7fffu + r;
  return (unsigned short)(u >> 16);
}

// anchor for flat index i (matches reference make_anchors incl. np.round half-even)
__device__ __forceinline__ void anchor_of(int i, float* o) {
  int pos = i / 15, a = i % 15;
  int iy = pos / 7, ix = pos % 7;
  int rr = a / 5, sc = a % 5;
  double ratio = (rr == 0) ? 0.5 : (rr == 1 ? 1.0 : 2.0);
  double scale = (double)(32 << sc);
  double hr = sqrt(ratio), wr = 1.0 / hr;
  double wsz = wr * scale, hsz = hr * scale;
  float bx1 = (float)rint(-wsz * 0.5), by1 = (float)rint(-hsz * 0.5);
  float bx2 = (float)rint(wsz * 0.5),  by2 = (float)rint(hsz * 0.5);
  float sx = (float)(ix * 32), sy = (float)(iy * 32);
  o[0] = sx + bx1; o[1] = sy + by1; o[2] = sx + bx2; o[3] = sy + by2;
}

// ---------------------------------------------------------------- sorting ----
__device__ __forceinline__ bool before_(float va, int ia, float vb, int ib) {
  return (va > vb) || (va == vb && ia < ib);
}

template<int NTOT, int NTH>
__device__ void bitonic_sort_sh(float* v, int* id) {
  const int t = threadIdx.x;
  for (int k = 2; k <= NTOT; k <<= 1) {
    for (int j = k >> 1; j > 0; j >>= 1) {
      for (int s = t; s < NTOT; s += NTH) {
        int p = s ^ j;
        if (p > s) {
          float v1 = v[s], v2 = v[p];
          int i1 = id[s], i2 = id[p];
          bool up = ((s & k) == 0);
          if (before_(v2, i2, v1, i1) == up) {
            v[s] = v2; id[s] = i2; v[p] = v1; id[p] = i1;
          }
        }
      }
      __syncthreads();
    }
  }
}

template<int NTOT, int NTH>
__device__ void bitonic_merge_sh(float* v, int* id) {
  const int t = threadIdx.x;
  for (int j = NTOT >> 1; j > 0; j >>= 1) {
    for (int s = t; s < NTOT; s += NTH) {
      int p = s ^ j;
      if (p > s) {
        float v1 = v[s], v2 = v[p];
        int i1 = id[s], i2 = id[p];
        if (before_(v2, i2, v1, i1)) {
          v[s] = v2; id[s] = i2; v[p] = v1; id[p] = i1;
        }
      }
    }
    __syncthreads();
  }
}

// ---------------------------------------------------------------- fused preprocessing ----
// blk [0,11520): f2b3 segments (fc2_w, bb_w, rpn_w, head-pack)
// blk [11520,11912): im2col backbone (bf16 out)
// blk [11912,20104): fc1_w permute -> W1p [p][n][c] bf16
__global__ __launch_bounds__(256) void k_pre(
    const float* __restrict__ fc2_w, unsigned short* __restrict__ w2b,
    const float* __restrict__ bb_w, unsigned short* __restrict__ w0b,
    const float* __restrict__ rpn_w, unsigned short* __restrict__ w3b,
    const float* __restrict__ cw, const float* __restrict__ bw,
    unsigned short* __restrict__ hwb,
    const float* __restrict__ images, unsigned short* __restrict__ patch,
    const float* __restrict__ fc1_w, unsigned short* __restrict__ w1p)
{
  __shared__ unsigned short tile[128 * 50];
  int blk = blockIdx.x;
  const int t = threadIdx.x;
  if (blk < 11520) {
    int i = (blk * 256 + t) * 4;
    const float* s; unsigned short* d; int off;
    if (i < 1048576) { s = fc2_w; d = w2b; off = i; }
    else if (i < 2097152) { s = bb_w; d = w0b; off = i - 1048576; }
    else if (i < 11534336) { s = rpn_w; d = w3b; off = i - 2097152; }
    else {
      int off4 = i - 11534336;              // [0, 262144)
      int row = off4 >> 10, col = off4 & 1023;
      ushort4 o;
      if (row < 37) {
        float4 v = *(const float4*)(cw + (size_t)row * 1024 + col);
        o.x = f2b(v.x); o.y = f2b(v.y); o.z = f2b(v.z); o.w = f2b(v.w);
      } else if (row < 185) {
        float4 v = *(const float4*)(bw + (size_t)(row - 37) * 1024 + col);
        o.x = f2b(v.x); o.y = f2b(v.y); o.z = f2b(v.z); o.w = f2b(v.w);
      } else {
        o.x = 0; o.y = 0; o.z = 0; o.w = 0;
      }
      *(ushort4*)(hwb + off4) = o;
      return;
    }
    float4 v = *(const float4*)(s + off);
    ushort4 o;
    o.x = f2b(v.x); o.y = f2b(v.y); o.z = f2b(v.z); o.w = f2b(v.w);
    *(ushort4*)(d + off) = o;
    return;
  }
  blk -= 11520;
  if (blk < 392) {
    int i = blk * 256 + t;
    if (i >= 98 * 1024) return;
    int rowi = i >> 10, k = i & 1023;
    int b = rowi / 49, pos = rowi % 49;
    int oy = pos / 7, ox = pos % 7;
    int ky = k >> 5, kx = k & 31;
    patch[i] = f2b(images[((size_t)b * 224 + oy * 32 + ky) * 224 + ox * 32 + kx]);
    return;
  }
  blk -= 392;
  // w1perm2: n = blk/8, ct = blk%8
  {
    const int n = blk >> 3, ct = blk & 7;
    const float* src = fc1_w + (size_t)n * 50176 + (size_t)ct * 128 * 49;
    for (int i = t; i < 6272; i += 256) {
      int cl = i / 49, p = i % 49;
      tile[cl * 50 + p] = f2b(src[i]);
    }
    __syncthreads();
    for (int j = t; j < 6272; j += 256) {
      int p = j >> 7, cl = j & 127;
      w1p[((size_t)p * 1024 + n) * 1024 + (size_t)ct * 128 + cl] = tile[cl * 50 + p];
    }
  }
}

// ---------------------------------------------------------------- bf16 MFMA GEMM ----
// 1-deep pipeline, named prefetch regs, ONE barrier per K-step, XCD-grouped swizzle.
// Msplit>0: M is laid out as [2][Msplit] rows (one image per 768-row half);
// gating is local_m < nvalid[img] and B is offset by img*boff.
__global__ __launch_bounds__(256) void k_gemm_bf16(
    const unsigned short* __restrict__ A, int lda, int M,
    const unsigned short* __restrict__ B, int ldb,
    float* __restrict__ P, int N, int Kchunk,
    const int* __restrict__ nvalid, int Msplit, int boff)
{
  __shared__ __attribute__((aligned(16))) unsigned short As[2][128][40]; // 32 data + 8 pad
  __shared__ __attribute__((aligned(16))) unsigned short Bs[2][128][40];
  const int G = gridDim.x * gridDim.y * gridDim.z;
  int lid = blockIdx.x + gridDim.x * (blockIdx.y + gridDim.y * blockIdx.z);
  lid = (lid & 7) * (G >> 3) + (lid >> 3);
  const int bx = lid % gridDim.x;
  const int rest = lid / gridDim.x;
  const int by = rest % gridDim.y, bz = rest / gridDim.y;
  const int m0 = bx * 128, n0 = by * 128;
  if (nvalid) {
    int img = (Msplit && m0 >= Msplit) ? 1 : 0;
    int lm = m0 - img * Msplit;
    if (lm >= nvalid[img]) return;
    B += (size_t)img * boff;
  }
  const int t = threadIdx.x;
  const int lane = t & 63, wid = t >> 6;
  const int wm = (wid >> 1) * 64, wn = (wid & 1) * 64;
  const size_t k0 = (size_t)bz * Kchunk;
  f32x4 acc[4][4];
#pragma unroll
  for (int i = 0; i < 4; ++i)
#pragma unroll
    for (int j = 0; j < 4; ++j) acc[i][j] = (f32x4){0.f, 0.f, 0.f, 0.f};
  const int r0 = t >> 2, c0 = (t & 3) * 8;
  const int fr = lane & 15, fk = (lane >> 4) * 8;
  const int gmA0 = m0 + r0, gmA1 = m0 + r0 + 64;
  const bool vA0 = gmA0 < M, vA1 = gmA1 < M;
  const unsigned short* pA0 = A + (size_t)gmA0 * lda + k0 + c0;
  const unsigned short* pA1 = A + (size_t)gmA1 * lda + k0 + c0;
  const unsigned short* pB0 = B + (size_t)(n0 + r0) * ldb + k0 + c0;
  const unsigned short* pB1 = B + (size_t)(n0 + r0 + 64) * ldb + k0 + c0;
  bf16x8 rA0 = {}, rA1 = {}, rB0, rB1;
  if (vA0) rA0 = *(const bf16x8*)pA0;
  if (vA1) rA1 = *(const bf16x8*)pA1;
  rB0 = *(const bf16x8*)pB0;
  rB1 = *(const bf16x8*)pB1;
  const int nt = Kchunk >> 5;
  int cur = 0;
  for (int it = 0; it < nt; ++it) {
    *(bf16x8*)&As[cur][r0][c0] = rA0;
    *(bf16x8*)&As[cur][r0 + 64][c0] = rA1;
    *(bf16x8*)&Bs[cur][r0][c0] = rB0;
    *(bf16x8*)&Bs[cur][r0 + 64][c0] = rB1;
    __syncthreads();
    if (it + 1 < nt) {
      size_t ofs = (size_t)(it + 1) * 32;
      rA0 = vA0 ? *(const bf16x8*)(pA0 + ofs) : (bf16x8){};
      rA1 = vA1 ? *(const bf16x8*)(pA1 + ofs) : (bf16x8){};
      rB0 = *(const bf16x8*)(pB0 + ofs);
      rB1 = *(const bf16x8*)(pB1 + ofs);
    }
    bf16x8 af[4], bg[4];
#pragma unroll
    for (int i = 0; i < 4; ++i) af[i] = *(const bf16x8*)&As[cur][wm + i * 16 + fr][fk];
#pragma unroll
    for (int j = 0; j < 4; ++j) bg[j] = *(const bf16x8*)&Bs[cur][wn + j * 16 + fr][fk];
#pragma unroll
    for (int i = 0; i < 4; ++i)
#pragma unroll
      for (int j = 0; j < 4; ++j)
        acc[i][j] = __builtin_amdgcn_mfma_f32_16x16x32_bf16(af[i], bg[j], acc[i][j], 0, 0, 0);
    cur ^= 1;
  }
  // epilogue: C/D layout col=lane&15, row=(lane>>4)*4+reg  [m89/m91 verified]
  float* Pp = P + (size_t)bz * M * N;
#pragma unroll
  for (int i = 0; i < 4; ++i) {
#pragma unroll
    for (int r = 0; r < 4; ++r) {
      int gm = m0 + wm + i * 16 + (lane >> 4) * 4 + r;
      if (gm < M) {
#pragma unroll
        for (int j = 0; j < 4; ++j)
          Pp[(size_t)gm * N + n0 + wn + j * 16 + (lane & 15)] = acc[i][j][r];
      }
    }
  }
}

// ---------------------------------------------------------------- im2col_rpn + M-GEMM (fused) ----
// blk [0,3528): im2col for RPN 3x3 conv (reads bbh).
// blk [3528,3920): M-GEMM writing Bmat transposed (identical to prior k_gemm_mb, G=392).
__global__ __launch_bounds__(256) void k_imrpn_mb(
    const unsigned short* __restrict__ bbh,
    unsigned short* __restrict__ im2,
    const unsigned short* __restrict__ W1p,
    unsigned short* __restrict__ Bmat)
{
  __shared__ __attribute__((aligned(16))) unsigned short As[2][128][40];
  __shared__ __attribute__((aligned(16))) unsigned short Bs[2][128][40];
  __shared__ unsigned short tile[98][130];
  const int t = threadIdx.x;
  int blk = blockIdx.x;
  if (blk < 3528) {
    int i = blk * 256 + t;
    if (i >= 98 * 9216) return;
    int rowi = i / 9216, k = i % 9216;
    int b = rowi / 49, pos = rowi % 49;
    int oy = pos / 7, ox = pos % 7;
    int ic = k / 9, kk = k % 9;
    int ky = kk / 3, kx = kk % 3;
    int y = oy + ky - 1, x = ox + kx - 1;
    unsigned short v = 0;
    if ((unsigned)y < 7u && (unsigned)x < 7u)
      v = bbh[((size_t)(b * 49 + y * 7 + x)) * 1024 + ic];
    im2[i] = v;
    return;
  }
  int lid = blk - 3528;                       // [0,392)
  lid = (lid & 7) * 49 + (lid >> 3);          // XCD swizzle, G=392
  const int by = lid % 8, p = lid / 8;
  const int n0 = by * 128;
  const int M = 98;
  const unsigned short* B = W1p + (size_t)p * 1048576;
  const int lane = t & 63, wid = t >> 6;
  const int wm = (wid >> 1) * 64, wn = (wid & 1) * 64;
  f32x4 acc[4][4];
#pragma unroll
  for (int i = 0; i < 4; ++i)
#pragma unroll
    for (int j = 0; j < 4; ++j) acc[i][j] = (f32x4){0.f, 0.f, 0.f, 0.f};
  const int r0 = t >> 2, c0 = (t & 3) * 8;
  const int fr = lane & 15, fk = (lane >> 4) * 8;
  int gA0 = r0; if (gA0 >= M) gA0 = M - 1;
  int gA1 = r0 + 64; if (gA1 >= M) gA1 = M - 1;
  const unsigned short* pA0 = bbh + (size_t)gA0 * 1024 + c0;
  const unsigned short* pA1 = bbh + (size_t)gA1 * 1024 + c0;
  const unsigned short* pB0 = B + (size_t)(n0 + r0) * 1024 + c0;
  const unsigned short* pB1 = B + (size_t)(n0 + r0 + 64) * 1024 + c0;
  bf16x8 rA0 = *(const bf16x8*)pA0;
  bf16x8 rA1 = *(const bf16x8*)pA1;
  bf16x8 rB0 = *(const bf16x8*)pB0;
  bf16x8 rB1 = *(const bf16x8*)pB1;
  const int nt = 1024 >> 5;
  int cur = 0;
  for (int it = 0; it < nt; ++it) {
    *(bf16x8*)&As[cur][r0][c0] = rA0;
    *(bf16x8*)&As[cur][r0 + 64][c0] = rA1;
    *(bf16x8*)&Bs[cur][r0][c0] = rB0;
    *(bf16x8*)&Bs[cur][r0 + 64][c0] = rB1;
    __syncthreads();
    if (it + 1 < nt) {
      size_t ofs = (size_t)(it + 1) * 32;
      rA0 = *(const bf16x8*)(pA0 + ofs);
      rA1 = *(const bf16x8*)(pA1 + ofs);
      rB0 = *(const bf16x8*)(pB0 + ofs);
      rB1 = *(const bf16x8*)(pB1 + ofs);
    }
    bf16x8 af[4], bg[4];
#pragma unroll
    for (int i = 0; i < 4; ++i) af[i] = *(const bf16x8*)&As[cur][wm + i * 16 + fr][fk];
#pragma unroll
    for (int j = 0; j < 4; ++j) bg[j] = *(const bf16x8*)&Bs[cur][wn + j * 16 + fr][fk];
#pragma unroll
    for (int i = 0; i < 4; ++i)
#pragma unroll
      for (int j = 0; j < 4; ++j)
        acc[i][j] = __builtin_amdgcn_mfma_f32_16x16x32_bf16(af[i], bg[j], acc[i][j], 0, 0, 0);
    cur ^= 1;
  }
  __syncthreads();
#pragma unroll
  for (int i = 0; i < 4; ++i) {
#pragma unroll
    for (int r = 0; r < 4; ++r) {
      int gm = wm + i * 16 + (lane >> 4) * 4 + r;
      if (gm < M) {
#pragma unroll
        for (int j = 0; j < 4; ++j)
          tile[gm][wn + j * 16 + (lane & 15)] = f2b(acc[i][j][r]);
      }
    }
  }
  __syncthreads();
  {
    int nl = t >> 1, b2 = t & 1;
    unsigned short* dst = Bmat + (size_t)(n0 + nl) * KF1 + b2 * KHALF + p * 49;
    for (int qq = 0; qq < 49; ++qq) dst[qq] = tile[b2 * 49 + qq][nl];
  }
  if (p == 0) {  // zero pad cols 2401..2431 in each half (avoid garbage in MFMA)
    for (int j2 = t; j2 < 128 * 62; j2 += 256) {
      int nl = j2 / 62, e = j2 % 62;
      int bb = e >= 31 ? 1 : 0;
      int col = bb * KHALF + 2401 + (e - bb * 31);
      Bmat[(size_t)(n0 + nl) * KF1 + col] = 0;
    }
  }
}

// ---------------------------------------------------------------- G build ----
// Gmat rows laid out [2][768]; row rg = b*768+r holds only its image's K-half.
__global__ __launch_bounds__(256) void k_gbuild(const float* __restrict__ props,
                                                unsigned short* __restrict__ Gmat)
{
#pragma clang fp contract(off)
  int rg = blockIdx.x;
  int b = rg / MROW, r = rg % MROW;
  __shared__ float g[KHALF];
  int t = threadIdx.x;
  for (int j = t; j < KHALF; j += 256) g[j] = 0.f;
  __syncthreads();
  if (t < 49) {
    int pr = b * NANCH + r; if (pr > 2 * NANCH - 1) pr = 2 * NANCH - 1;
    const float* roi = props + (size_t)pr * 4;
    int p = t, oy = p / 7, ox = p % 7;
    float x1 = roi[0] * 0.03125f, y1 = roi[1] * 0.03125f;
    float rw = fmaxf(roi[2] * 0.03125f - x1, 1.f);
    float rh = fmaxf(roi[3] * 0.03125f - y1, 1.f);
    float bw = rw / 7.f, bh = rh / 7.f;
    float* gb = g + p * 49;
    for (int iy = 0; iy < 2; ++iy) {
      for (int ix = 0; ix < 2; ++ix) {
        float ys = y1 + ((float)oy + ((float)iy + 0.5f) * 0.5f) * bh;
        float xs = x1 + ((float)ox + ((float)ix + 0.5f) * 0.5f) * bw;
        bool vy = (ys >= -1.f) && (ys <= 7.f);
        bool vx = (xs >= -1.f) && (xs <= 7.f);
        float yc = fmaxf(ys, 0.f), xc = fmaxf(xs, 0.f);
        int y0 = min(max((int)floorf(yc), 0), 6), x0 = min(max((int)floorf(xc), 0), 6);
        int y1i = min(y0 + 1, 6), x1i = min(x0 + 1, 6);
        if (y0 == 6) yc = 6.f;
        if (x0 == 6) xc = 6.f;
        float ly = yc - (float)y0, lx = xc - (float)x0;
        float hy = 1.f - ly, hx = 1.f - lx;
        float vm = (vy && vx) ? 0.25f : 0.f;
        gb[y0 * 7 + x0]   += hy * hx * vm;
        gb[y0 * 7 + x1i]  += hy * lx * vm;
        gb[y1i * 7 + x0]  += ly * hx * vm;
        gb[y1i * 7 + x1i] += ly * lx * vm;
      }
    }
  }
  __syncthreads();
  unsigned short* Gr = Gmat + (size_t)rg * KHALF;
  for (int j = t; j < KHALF; j += 256) Gr[j] = f2b(g[j]);
}

// flags: 1=overwrite(dst ignored), 2=add bias, 4=relu, 8=write bf16 to dst16,
//        16=skip fp32 dst write
__global__ void k_reduce(const float* __restrict__ P, float* __restrict__ dst,
                         unsigned short* __restrict__ dst16,
                         int S, int M, int N, const float* __restrict__ bias, int flags)
{
  size_t i = (size_t)blockIdx.x * 256 + threadIdx.x;
  size_t tot = (size_t)M * N;
  if (i >= tot) return;
  float v = (flags & 1) ? 0.f : dst[i];
  for (int s = 0; s < S; ++s) v += P[(size_t)s * tot + i];
  if (flags & 2) v += bias[i % (size_t)N];
  if (flags & 4) v = fmaxf(v, 0.f);
  if (!(flags & 16)) dst[i] = v;
  if (flags & 8) dst16[i] = f2b(v);
}

// ---------------------------------------------------------------- RPN heads ----
__global__ __launch_bounds__(256) void k_rpn_head(
    const float* __restrict__ tmn, const float* __restrict__ cls_w,
    const float* __restrict__ cls_b, const float* __restrict__ reg_w,
    const float* __restrict__ reg_b, float* __restrict__ obj, float* __restrict__ reg)
{
  int blk = blockIdx.x;
  __shared__ float col[1024];
  const float* row = tmn + (size_t)blk * 1024;
  for (int i = threadIdx.x; i < 1024; i += 256) col[i] = row[i];
  __syncthreads();
  int b = blk / 49, pos = blk % 49;
  for (int o = threadIdx.x; o < 75; o += 256) {
    const float* w = (o < 15) ? (cls_w + (size_t)o * 1024) : (reg_w + (size_t)(o - 15) * 1024);
    float s = 0.f;
    for (int k = 0; k < 1024; ++k) s = fmaf(col[k], w[k], s);
    if (o < 15) {
      obj[(size_t)b * NANCH + pos * 15 + o] = s + cls_b[o];
    } else {
      int c = o - 15, a = c >> 2, d = c & 3;
      reg[((size_t)b * NANCH + pos * 15 + a) * 4 + d] = s + reg_b[c];
    }
  }
}

// ---------------------------------------------------------------- RPN stage 1 ----
__global__ __launch_bounds__(1024) void k_rpn_prep(
    const float* __restrict__ obj, const float* __restrict__ reg,
    float* __restrict__ bxp, float* __restrict__ pnms)
{
#pragma clang fp contract(off)
  const int b = blockIdx.x, t = threadIdx.x;
  __shared__ float sval[1024];
  __shared__ float vo1[1024];
  __shared__ int o1a[1024];
  __shared__ int wtv[16];
  __shared__ int wti[16];
  sval[t] = (t < NANCH) ? obj[(size_t)b * NANCH + t] : -INFINITY;
  __syncthreads();
  {
    float v = sval[t];
    int rank = 0;
    for (int j = 0; j < NANCH; ++j) {
      float u = sval[j];
      rank += (u > v) || (u == v && j < t);
    }
    if (t < NANCH) { vo1[rank] = v; o1a[rank] = t; }
  }
  __syncthreads();
  float x1 = 0.f, y1 = 0.f, x2 = 0.f, y2 = 0.f, prob = -1.f;
  bool flag = false;
  if (t < NANCH) {
    int ai = o1a[t];
    const float* d = reg + ((size_t)b * NANCH + ai) * 4;
    float an[4];
    anchor_of(ai, an);
    float aw = an[2] - an[0], ah = an[3] - an[1];
    float acx = an[0] + 0.5f * aw, acy = an[1] + 0.5f * ah;
    float dw = fminf(d[2], BBCLIP), dh = fminf(d[3], BBCLIP);
    float pcx = d[0] * aw + acx, pcy = d[1] * ah + acy;
    float pw = expf(dw) * aw, ph = expf(dh) * ah;
    x1 = pcx - 0.5f * pw; y1 = pcy - 0.5f * ph;
    x2 = pcx + 0.5f * pw; y2 = pcy + 0.5f * ph;
    x1 = fminf(fmaxf(x1, 0.f), 224.f);
    y1 = fminf(fmaxf(y1, 0.f), 224.f);
    x2 = fminf(fmaxf(x2, 0.f), 224.f);
    y2 = fminf(fmaxf(y2, 0.f), 224.f);
    flag = (x2 - x1 >= 1e-3f) && (y2 - y1 >= 1e-3f);
    prob = 1.f / (1.f + expf(-vo1[t]));
  }
  bool iflag = (t < NANCH) && !flag;
  unsigned long long balv = __ballot(flag);
  unsigned long long bali = __ballot(iflag);
  int lane = t & 63, w = t >> 6;
  if (lane == 0) { wtv[w] = __popcll(balv); wti[w] = __popcll(bali); }
  __syncthreads();
  int nval = 0, basev = 0, basei = 0;
  for (int k = 0; k < 16; ++k) {
    int cv = wtv[k], ci = wti[k];
    nval += cv;
    if (k < w) { basev += cv; basei += ci; }
  }
  if (t < NANCH) {
    unsigned long long lm = (1ull << lane) - 1;
    int pos = flag ? (basev + __popcll(balv & lm))
                   : (nval + basei + __popcll(bali & lm));
    float* o = bxp + ((size_t)b * NANCH + pos) * 4;
    o[0] = x1; o[1] = y1; o[2] = x2; o[3] = y2;
    pnms[(size_t)b * NANCH + pos] = flag ? prob : -1.f;
  }
}

// ---------------------------------------------------------------- RPN stage 2 ----
__global__ __launch_bounds__(256) void k_rpn_mask(
    const float* __restrict__ bxp, unsigned long long* __restrict__ rmask)
{
#pragma clang fp contract(off)
  int blk = blockIdx.x;
  int b = blk / 35;
  int row = (blk % 35) * 21 + (int)(threadIdx.x / 12);
  int w = threadIdx.x % 12;
  if (threadIdx.x >= 252 || row >= NANCH) return;
  const float* a = bxp + ((size_t)b * NANCH + row) * 4;
  float a0 = a[0], a1 = a[1], a2 = a[2], a3 = a[3];
  float aarea = (a2 - a0) * (a3 - a1);
  int l0 = w * 64;
  int l1 = (l0 + 64 < NANCH) ? l0 + 64 : NANCH;
  int ls = (l0 > row + 1) ? l0 : row + 1;
  unsigned long long bits = 0ull;
  for (int l = ls; l < l1; ++l) {
    const float* q = bxp + ((size_t)b * NANCH + l) * 4;
    float b0 = q[0], b1 = q[1], b2 = q[2], b3 = q[3];
    float barea = (b2 - b0) * (b3 - b1);
    float ix1 = fmaxf(a0, b0), iy1 = fmaxf(a1, b1);
    float ix2 = fminf(a2, b2), iy2 = fminf(a3, b3);
    float iw = fmaxf(ix2 - ix1, 0.f), ih = fmaxf(iy2 - iy1, 0.f);
    float inter = iw * ih;
    float iou = inter / fmaxf(aarea + barea - inter, 1e-9f);
    if (iou > 0.7f) bits |= 1ull << (l & 63);
  }
  rmask[((size_t)b * NANCH + row) * 12 + w] = bits;
}

// ---------------------------------------------------------------- RPN stage 3 ----
__global__ __launch_bounds__(1024) void k_rpn_fin(
    const float* __restrict__ bxp, const float* __restrict__ pnms,
    const unsigned long long* __restrict__ rmask,
    float* __restrict__ props, int* __restrict__ meta)
{
  const int b = blockIdx.x, t = threadIdx.x;
  __shared__ unsigned long long smask[NANCH * 12];
  __shared__ float sp[1024];
  __shared__ unsigned long long keepw[12];
  __shared__ int wtot[16];
  for (int i = t; i < NANCH * 12; i += 1024)
    smask[i] = rmask[(size_t)b * NANCH * 12 + i];
  sp[t] = (t < NANCH) ? pnms[(size_t)b * NANCH + t] : -1.f;
  __syncthreads();
  if (t < 64) {
    unsigned long long kl = (t < 12) ? ~0ull : 0ull;
    for (int i = 0; i < NANCH; ++i) {
      unsigned long long kw = __shfl(kl, i >> 6);
      unsigned long long m = (t < 12) ? smask[i * 12 + t] : 0ull;
      bool on = (kw >> (i & 63)) & 1ull;
      kl &= on ? ~m : ~0ull;
    }
    if (t < 12) keepw[t] = kl;
  }
  __syncthreads();
  bool flag = false;
  if (t < NANCH) {
    bool kp = (keepw[t >> 6] >> (t & 63)) & 1ull;
    flag = kp && (sp[t] > 0.f);
  }
  unsigned long long bal = __ballot(flag);
  int lane = t & 63, w = t >> 6;
  if (lane == 0) wtot[w] = __popcll(bal);
  __syncthreads();
  int base = 0, tot = 0;
  for (int k = 0; k < 16; ++k) { int c = wtot[k]; if (k < w) base += c; tot += c; }
  if (flag) {
    int pos = base + __popcll(bal & ((1ull << lane) - 1));
    const float* src = bxp + ((size_t)b * NANCH + t) * 4;
    float* o = props + ((size_t)b * NANCH + pos) * 4;
    o[0] = src[0]; o[1] = src[1]; o[2] = src[2]; o[3] = src[3];
  }
  if (t == 0) meta[b] = tot;
}

// ---------------------------------------------------------------- candidates + top2048 (fused) ----
// Phase A: per-image candidate decode from head GEMM P ([z][MTOT][256] fp32).
// Phase B: top-2048 selection (identical to prior k_top2048).
__global__ __launch_bounds__(1024) void k_candtop(
    const float* __restrict__ P, const float* __restrict__ cb_,
    const float* __restrict__ bb_, const float* __restrict__ props,
    const int* __restrict__ meta,
    float* __restrict__ cscore, float* __restrict__ cbox,
    float* __restrict__ sel_score, int* __restrict__ sel_cidx,
    int* __restrict__ metao)
{
#pragma clang fp contract(off)
  const int b = blockIdx.x, t = threadIdx.x;
  __shared__ float Lv[2048]; __shared__ int Li[2048];
  __shared__ float Cv[2048]; __shared__ int Ci[2048];
  __shared__ int cnt;
  float* cs = cscore + (size_t)b * NCANDP;
  float* cbx = cbox + (size_t)b * NCANDP * 4;
  // ---- phase A: candidates for this image's rois ----
  {
    int nv = meta[b];
    for (int r = t; r < NANCH; r += 1024) {
      int base = r * 36;
      if (r >= nv) {
        for (int j = 0; j < 36; ++j) {
          cs[base + j] = -1.f;
          float* q = cbx + (size_t)(base + j) * 4;
          q[0] = 0.f; q[1] = 0.f; q[2] = 0.f; q[3] = 0.f;
        }
        continue;
      }
      int row = b * MROW + r;
      const float* p0 = P + (size_t)row * 256;
      const float* p1 = P + (size_t)MTOT * 256 + (size_t)row * 256;
      float lg[37];
      for (int c = 0; c < 37; ++c) lg[c] = p0[c] + p1[c] + cb_[c];
      float mx = lg[0];
      for (int c = 1; c < 37; ++c) mx = fmaxf(mx, lg[c]);
      float sum = 0.f;
      for (int c = 0; c < 37; ++c) sum += expf(lg[c] - mx);
      int rg = b * NANCH + r;
      const float* roi = props + (size_t)rg * 4;
      float rw = roi[2] - roi[0], rh = roi[3] - roi[1];
      float rcx = roi[0] + 0.5f * rw, rcy = roi[1] + 0.5f * rh;
      for (int c = 1; c < 37; ++c) {
        float d0 = p0[37 + c * 4]     + p1[37 + c * 4]     + bb_[c * 4];
        float d1 = p0[37 + c * 4 + 1] + p1[37 + c * 4 + 1] + bb_[c * 4 + 1];
        float d2 = p0[37 + c * 4 + 2] + p1[37 + c * 4 + 2] + bb_[c * 4 + 2];
        float d3 = p0[37 + c * 4 + 3] + p1[37 + c * 4 + 3] + bb_[c * 4 + 3];
        float dx = d0 / 10.f, dy = d1 / 10.f;
        float dw = fminf(d2 / 5.f, BBCLIP), dh = fminf(d3 / 5.f, BBCLIP);
        float pcx = dx * rw + rcx, pcy = dy * rh + rcy;
        float pw = expf(dw) * rw, ph = expf(dh) * rh;
        float x1 = pcx - 0.5f * pw, y1 = pcy - 0.5f * ph;
        float x2 = pcx + 0.5f * pw, y2 = pcy + 0.5f * ph;
        x1 = fminf(fmaxf(x1, 0.f), 224.f);
        y1 = fminf(fmaxf(y1, 0.f), 224.f);
        x2 = fminf(fmaxf(x2, 0.f), 224.f);
        y2 = fminf(fmaxf(y2, 0.f), 224.f);
        float sc = expf(lg[c] - mx) / sum;
        bool ok = ((x2 - x1) >= 1e-2f) && ((y2 - y1) >= 1e-2f) && (sc > 0.05f);
        cs[base + c - 1] = ok ? sc : -1.f;
        float* q = cbx + (size_t)(base + c - 1) * 4;
        q[0] = x1; q[1] = y1; q[2] = x2; q[3] = y2;
      }
    }
  }
  if (t == 0) cnt = 0;
  __syncthreads();
  // ---- phase B: top-2048 (identical to prior kernel) ----
  for (int gi = t; gi < NCAND; gi += 1024) {
    float v = cs[gi];
    if (v > 0.f) {
      int p = atomicAdd(&cnt, 1);
      if (p < 2048) { Cv[p] = v; Ci[p] = gi; }
    }
  }
  __syncthreads();
  int npos = cnt;
  if (npos <= 2048) {
    for (int h = 0; h < 2; ++h) {
      int p = h * 1024 + t;
      if (p < npos) {
        float v = Cv[p]; int id = Ci[p];
        int rank = 0;
        for (int j = 0; j < npos; ++j) {
          float u = Cv[j]; int ju = Ci[j];
          rank += (u > v) || (u == v && ju < id);
        }
        sel_score[b * 2048 + rank] = v;
        sel_cidx[b * 2048 + rank] = id;
      }
      if (p >= npos && p < 2048) {
        sel_score[b * 2048 + p] = -1.f;
        sel_cidx[b * 2048 + p] = 0;
      }
    }
    if (t == 0) metao[2 + b] = npos;
    return;
  }
  for (int chunk = 0; chunk < 13; ++chunk) {
    for (int s = t; s < 2048; s += 1024) {
      int gi = chunk * 2048 + s;
      Cv[s] = (gi < NCAND) ? cs[gi] : -INFINITY;
      Ci[s] = gi;
    }
    __syncthreads();
    bitonic_sort_sh<2048, 1024>(Cv, Ci);
    if (chunk == 0) {
      for (int s = t; s < 2048; s += 1024) { Lv[s] = Cv[s]; Li[s] = Ci[s]; }
      __syncthreads();
    } else {
      for (int s = t; s < 2048; s += 1024) {
        float cv = Cv[2047 - s]; int ci = Ci[2047 - s];
        if (before_(cv, ci, Lv[s], Li[s])) { Lv[s] = cv; Li[s] = ci; }
      }
      __syncthreads();
      bitonic_merge_sh<2048, 1024>(Lv, Li);
    }
  }
  for (int s = t; s < 2048; s += 1024) {
    sel_score[b * 2048 + s] = Lv[s];
    sel_cidx[b * 2048 + s] = Li[s];
  }
  if (t == 0) metao[2 + b] = 2048;
}

// ---------------------------------------------------------------- det NMS mask ----
__global__ void k_detmask(const int* __restrict__ sel_cidx,
                          const float* __restrict__ cbox,
                          const int* __restrict__ meta,
                          unsigned long long* __restrict__ dmask)
{
#pragma clang fp contract(off)
  int blk = blockIdx.x;
  int b = blk >> 8, row0 = (blk & 255) * 8;
  int npos = meta[2 + b];
  if (row0 >= npos) return;
  int t = threadIdx.x;
  int i = row0 + (t >> 5), w = t & 31;
  if (i >= npos) return;
  int ci = sel_cidx[b * 2048 + i];
  const float* bp = cbox + ((size_t)b * NCANDP + ci) * 4;
  float off = (float)(ci % 36 + 1) * 225.f;
  float a0 = bp[0] + off, a1 = bp[1] + off, a2 = bp[2] + off, a3 = bp[3] + off;
  float aarea = (a2 - a0) * (a3 - a1);
  unsigned long long bits = 0ull;
  int l0 = w * 64;
  int l1 = (l0 + 64 < npos) ? l0 + 64 : npos;
  int ls = (l0 > i + 1) ? l0 : i + 1;
  for (int l = ls; l < l1; ++l) {
    int cl = sel_cidx[b * 2048 + l];
    const float* q = cbox + ((size_t)b * NCANDP + cl) * 4;
    float o2 = (float)(cl % 36 + 1) * 225.f;
    float b0 = q[0] + o2, b1 = q[1] + o2, b2 = q[2] + o2, b3 = q[3] + o2;
    float barea = (b2 - b0) * (b3 - b1);
    float ix1 = fmaxf(a0, b0), iy1 = fmaxf(a1, b1);
    float ix2 = fminf(a2, b2), iy2 = fminf(a3, b3);
    float iw = fmaxf(ix2 - ix1, 0.f), ih = fmaxf(iy2 - iy1, 0.f);
    float inter = iw * ih;
    float iou = inter / fmaxf(aarea + barea - inter, 1e-9f);
    if (iou > 0.5f) bits |= 1ull << (l & 63);
  }
  dmask[((size_t)b * 2048 + i) * 32 + w] = bits;
}

// ---------------------------------------------------------------- final ----
__global__ __launch_bounds__(1024) void k_final(
    const float* __restrict__ sel_score, const int* __restrict__ sel_cidx,
    const float* __restrict__ cbox, const unsigned long long* __restrict__ dmask,
    const int* __restrict__ meta, float* __restrict__ out)
{
  const int b = blockIdx.x, t = threadIdx.x;
  __shared__ unsigned long long keepw[32];
  __shared__ float sv[2048];
  __shared__ float kv[2048]; __shared__ int ks[2048];
  __shared__ int wtot[32];
  int npos = meta[2 + b];
  for (int h = 0; h < 2; ++h) {
    int s = h * 1024 + t;
    sv[s] = sel_score[b * 2048 + s];
  }
  __syncthreads();
  if (t < 64) {
    unsigned long long kl = (t < 32) ? ~0ull : 0ull;
    for (int i = 0; i < npos; ++i) {
      unsigned long long kw = __shfl(kl, i >> 6);
      unsigned long long m = (t < 32) ? dmask[((size_t)b * 2048 + i) * 32 + t] : 0ull;
      bool on = (kw >> (i & 63)) & 1ull;
      kl &= on ? ~m : ~0ull;
    }
    if (t < 32) keepw[t] = kl;
  }
  __syncthreads();
  const int lane = t & 63, w = t >> 6;
  int s0 = t;
  bool f0 = ((keepw[s0 >> 6] >> (s0 & 63)) & 1ull) && (sv[s0] > 0.f);
  unsigned long long bal0 = __ballot(f0);
  if (lane == 0) wtot[w] = __popcll(bal0);
  int s1 = 1024 + t;
  bool f1 = ((keepw[s1 >> 6] >> (s1 & 63)) & 1ull) && (sv[s1] > 0.f);
  unsigned long long bal1 = __ballot(f1);
  if (lane == 0) wtot[16 + w] = __popcll(bal1);
  __syncthreads();
  int nk = 0, base0 = 0, base1 = 0;
  for (int k = 0; k < 32; ++k) {
    int c = wtot[k];
    if (k < w) base0 += c;
    if (k < 16 + w) base1 += c;
    nk += c;
  }
  int p0 = -1, p1 = -1;
  if (f0) { p0 = base0 + __popcll(bal0 & ((1ull << lane) - 1)); kv[p0] = sv[s0]; ks[p0] = s0; }
  if (f1) { p1 = base1 + __popcll(bal1 & ((1ull << lane) - 1)); kv[p1] = sv[s1]; ks[p1] = s1; }
  __syncthreads();
  if (f0) {
    float v = sv[s0]; int rank = 0;
    for (int j = 0; j < nk; ++j) { float u = kv[j]; int ju = ks[j]; rank += (u > v) || (u == v && ju < s0); }
    if (rank < 100) {
      int ci = sel_cidx[b * 2048 + s0];
      const float* bp = cbox + ((size_t)b * NCANDP + ci) * 4;
      float* o = out + ((size_t)b * 100 + rank) * 6;
      o[0] = bp[0]; o[1] = bp[1]; o[2] = bp[2]; o[3] = bp[3];
      o[4] = v; o[5] = (float)(ci % 36 + 1);
    }
  }
  if (f1) {
    float v = sv[s1]; int rank = 0;
    for (int j = 0; j < nk; ++j) { float u = kv[j]; int ju = ks[j]; rank += (u > v) || (u == v && ju < s1); }
    if (rank < 100) {
      int ci = sel_cidx[b * 2048 + s1];
      const float* bp = cbox + ((size_t)b * NCANDP + ci) * 4;
      float* o = out + ((size_t)b * 100 + rank) * 6;
      o[0] = bp[0]; o[1] = bp[1]; o[2] = bp[2]; o[3] = bp[3];
      o[4] = v; o[5] = (float)(ci % 36 + 1);
    }
  }
  if (t < 100 && t >= nk) {
    float* o = out + ((size_t)b * 100 + t) * 6;
    o[0] = 0.f; o[1] = 0.f; o[2] = 0.f; o[3] = 0.f; o[4] = 0.f; o[5] = 0.f;
  }
}

// ---------------------------------------------------------------- host ----
extern "C" void kernel_launch(void* const* d_in, const int* in_sizes, int n_in,
                              void* d_out, int out_size, void* d_ws, size_t ws_size,
                              hipStream_t stream)
{
  (void)in_sizes; (void)n_in; (void)out_size; (void)ws_size;
  const float* images = (const float*)d_in[0];
  const float* bb_w   = (const float*)d_in[1];
  const float* bb_b   = (const float*)d_in[2];
  const float* rpn_w  = (const float*)d_in[3];
  const float* rpn_b  = (const float*)d_in[4];
  const float* cls_w  = (const float*)d_in[5];
  const float* cls_b  = (const float*)d_in[6];
  const float* reg_w  = (const float*)d_in[7];
  const float* reg_b  = (const float*)d_in[8];
  const float* fc1_w  = (const float*)d_in[9];
  const float* fc1_b  = (const float*)d_in[10];
  const float* fc2_w  = (const float*)d_in[11];
  const float* fc2_b  = (const float*)d_in[12];
  const float* clsp_w = (const float*)d_in[13];
  const float* clsp_b = (const float*)d_in[14];
  const float* boxp_w = (const float*)d_in[15];
  const float* boxp_b = (const float*)d_in[16];
  float* out = (float*)d_out;
  char* ws = (char*)d_ws;

  size_t off = 0;
  auto alloc = [&](size_t bytes) -> size_t {
    size_t o = off; off = (off + bytes + 255) & ~(size_t)255; return o;
  };
  size_t o_patch = alloc(98ull * 1024 * 2);      // im2col backbone, bf16
  size_t o_bbC   = alloc(98ull * 1024 * 4);      // fp32 slot (unused data path, kept)
  size_t o_bbh   = alloc(98ull * 1024 * 2);      // F = feats bf16 (position-major)
  size_t o_t     = alloc(98ull * 1024 * 4);
  size_t o_im2   = alloc(98ull * 9216 * 2);      // im2col rpn, bf16
  size_t o_obj   = alloc(1470ull * 4);
  size_t o_reg   = alloc(1470ull * 16);
  size_t o_props = alloc(1470ull * 16);
  size_t o_bxp   = alloc(1470ull * 16);
  size_t o_pnms  = alloc(1470ull * 4);
  size_t o_rm    = alloc(1470ull * 12 * 8);
  size_t o_meta  = alloc(256);
  size_t o_y1    = alloc((size_t)MTOT * 1024 * 4);  // fp32 slot (unused data path)
  size_t o_cs    = alloc(2ull * NCANDP * 4);
  size_t o_cb    = alloc(2ull * NCANDP * 16);
  size_t o_ss    = alloc(2ull * 2048 * 4);
  size_t o_sc    = alloc(2ull * 2048 * 4);
  size_t o_dm    = alloc(2ull * 2048 * 32 * 8);
  size_t o_w0b   = alloc(1048576ull * 2);        // bb_w bf16
  size_t o_w3b   = alloc(9437184ull * 2);        // rpn_w bf16
  size_t o_w1p   = alloc(51380224ull * 2);       // W1p [49][1024][1024] bf16
  size_t o_bmat  = alloc(1024ull * KF1 * 2);     // Bmat [1024][4864] bf16
  size_t o_gmat  = alloc((size_t)MTOT * KHALF * 2); // Gmat [1536][2432] bf16
  size_t o_w2b   = alloc(1048576ull * 2);        // fc2_w bf16
  size_t o_hwb   = alloc(256ull * 1024 * 2);     // predictor heads packed bf16
  size_t o_y1b   = alloc((size_t)MTOT * 1024 * 2); // fc1 out bf16
  size_t o_y2b   = alloc((size_t)MTOT * 1024 * 2); // fc2 out bf16
  size_t o_P     = alloc(32ull * 98 * 1024 * 4 > 2ull * MTOT * 1024 * 4
                         ? 32ull * 98 * 1024 * 4 : 2ull * MTOT * 1024 * 4);

  unsigned short* patchb = (unsigned short*)(ws + o_patch);
  float* bbC   = (float*)(ws + o_bbC);
  unsigned short* bbh = (unsigned short*)(ws + o_bbh);
  float* tb    = (float*)(ws + o_t);
  unsigned short* im2b = (unsigned short*)(ws + o_im2);
  float* objb  = (float*)(ws + o_obj);
  float* regb  = (float*)(ws + o_reg);
  float* props = (float*)(ws + o_props);
  float* bxp   = (float*)(ws + o_bxp);
  float* pnms  = (float*)(ws + o_pnms);
  unsigned long long* rmb = (unsigned long long*)(ws + o_rm);
  int*   meta  = (int*)(ws + o_meta);
  float* y1    = (float*)(ws + o_y1);
  float* csb   = (float*)(ws + o_cs);
  float* cbb   = (float*)(ws + o_cb);
  float* ssb   = (float*)(ws + o_ss);
  int*   scb   = (int*)(ws + o_sc);
  unsigned long long* dmb = (unsigned long long*)(ws + o_dm);
  unsigned short* w0b = (unsigned short*)(ws + o_w0b);
  unsigned short* w3b = (unsigned short*)(ws + o_w3b);
  unsigned short* w1p = (unsigned short*)(ws + o_w1p);
  unsigned short* bmat = (unsigned short*)(ws + o_bmat);
  unsigned short* gmat = (unsigned short*)(ws + o_gmat);
  unsigned short* w2b = (unsigned short*)(ws + o_w2b);
  unsigned short* hwb = (unsigned short*)(ws + o_hwb);
  unsigned short* y1b = (unsigned short*)(ws + o_y1b);
  unsigned short* y2b = (unsigned short*)(ws + o_y2b);
  float* Pb    = (float*)(ws + o_P);

  // fused preprocessing: weight conversions + head pack + backbone im2col + fc1_w permute
  k_pre<<<20104, 256, 0, stream>>>(fc2_w, w2b, bb_w, w0b, rpn_w, w3b,
                                   clsp_w, boxp_w, hwb, images, patchb, fc1_w, w1p);
  // backbone conv as bf16 MFMA GEMM, z=8; bf16-only output (F = bbh)
  k_gemm_bf16<<<dim3(1, 8, 8), 256, 0, stream>>>(patchb, 1024, 98, w0b, 1024, Pb, 1024, 128, nullptr, 0, 0);
  k_reduce<<<392, 256, 0, stream>>>(Pb, bbC, bbh, 8, 98, 1024, bb_b, 31);
  // fused: RPN im2col + M-GEMM (Bmat direct)
  k_imrpn_mb<<<3920, 256, 0, stream>>>(bbh, im2b, w1p, bmat);
  // RPN 3x3 conv as bf16 MFMA GEMM, z=32
  k_gemm_bf16<<<dim3(1, 8, 32), 256, 0, stream>>>(im2b, 9216, 98, w3b, 9216, Pb, 1024, 288, nullptr, 0, 0);
  k_reduce<<<392, 256, 0, stream>>>(Pb, tb, nullptr, 32, 98, 1024, rpn_b, 7);
  // RPN 1x1 heads + proposal filtering (3-stage, CU-parallel IoU mask)
  k_rpn_head<<<98, 256, 0, stream>>>(tb, cls_w, cls_b, reg_w, reg_b, objb, regb);
  k_rpn_prep<<<2, 1024, 0, stream>>>(objb, regb, bxp, pnms);
  k_rpn_mask<<<70, 256, 0, stream>>>(bxp, rmb);
  k_rpn_fin<<<2, 1024, 0, stream>>>(bxp, pnms, rmb, props, meta);
  // RoIAlign-as-linear-op: G build ([1536][2432]), fc1 = G @ Bmat[img-half]^T (K=2432, z=2)
  k_gbuild<<<MTOT, 256, 0, stream>>>(props, gmat);
  k_gemm_bf16<<<dim3(12, 8, 2), 256, 0, stream>>>(gmat, KHALF, MTOT, bmat, KF1, Pb, 1024, 1216, meta, MROW, KHALF);
  k_reduce<<<6144, 256, 0, stream>>>(Pb, y1, y1b, 2, MTOT, 1024, fc1_b, 31);
  // fc2 via bf16 MFMA, z=2; bf16-only output
  k_gemm_bf16<<<dim3(12, 8, 2), 256, 0, stream>>>(y1b, 1024, MTOT, w2b, 1024, Pb, 1024, 512, meta, MROW, 0);
  k_reduce<<<6144, 256, 0, stream>>>(Pb, y1, y2b, 2, MTOT, 1024, fc2_b, 31);
  // predictor heads as bf16 MFMA GEMM (M=1536, N=256 packed, z=2), then fused cand+top2048
  k_gemm_bf16<<<dim3(12, 2, 2), 256, 0, stream>>>(y2b, 1024, MTOT, hwb, 1024, Pb, 256, 512, meta, MROW, 0);
  k_candtop<<<2, 1024, 0, stream>>>(Pb, clsp_b, boxp_b, props, meta, csb, cbb, ssb, scb, meta);
  // class-wise NMS, top-100
  k_detmask<<<512, 256, 0, stream>>>(scb, cbb, meta, dmb);
  k_final<<<2, 1024, 0, stream>>>(ssb, scb, cbb, dmb, meta, out);
}

// Round 23
// 442.668 us; speedup vs baseline: 1.1699x; 1.1699x over previous
//
#include <hip/hip_runtime.h>
#include <math.h>

#define NANCH 735
#define NCAND 26460     // 735*36
#define NCANDP 26624    // 13*2048
#define BBCLIP 4.135166556742356f
#define KF1 4864        // fc1 factored K: 2 images * (49*49=2401 padded to 2432)
#define KHALF 2432
#define MROW 768        // padded rows per image in roi-major tensors
#define MTOT 1536

typedef short bf16x8 __attribute__((ext_vector_type(8)));
typedef float f32x4 __attribute__((ext_vector_type(4)));

__device__ __forceinline__ unsigned short f2b(float f) {
  unsigned int u = __float_as_uint(f);
  unsigned int r = (u >> 16) & 1u;
  u += 0x7fffu + r;
  return (unsigned short)(u >> 16);
}

// anchor for flat index i (matches reference make_anchors incl. np.round half-even)
__device__ __forceinline__ void anchor_of(int i, float* o) {
  int pos = i / 15, a = i % 15;
  int iy = pos / 7, ix = pos % 7;
  int rr = a / 5, sc = a % 5;
  double ratio = (rr == 0) ? 0.5 : (rr == 1 ? 1.0 : 2.0);
  double scale = (double)(32 << sc);
  double hr = sqrt(ratio), wr = 1.0 / hr;
  double wsz = wr * scale, hsz = hr * scale;
  float bx1 = (float)rint(-wsz * 0.5), by1 = (float)rint(-hsz * 0.5);
  float bx2 = (float)rint(wsz * 0.5),  by2 = (float)rint(hsz * 0.5);
  float sx = (float)(ix * 32), sy = (float)(iy * 32);
  o[0] = sx + bx1; o[1] = sy + by1; o[2] = sx + bx2; o[3] = sy + by2;
}

// ---------------------------------------------------------------- sorting ----
__device__ __forceinline__ bool before_(float va, int ia, float vb, int ib) {
  return (va > vb) || (va == vb && ia < ib);
}

template<int NTOT, int NTH>
__device__ void bitonic_sort_sh(float* v, int* id) {
  const int t = threadIdx.x;
  for (int k = 2; k <= NTOT; k <<= 1) {
    for (int j = k >> 1; j > 0; j >>= 1) {
      for (int s = t; s < NTOT; s += NTH) {
        int p = s ^ j;
        if (p > s) {
          float v1 = v[s], v2 = v[p];
          int i1 = id[s], i2 = id[p];
          bool up = ((s & k) == 0);
          if (before_(v2, i2, v1, i1) == up) {
            v[s] = v2; id[s] = i2; v[p] = v1; id[p] = i1;
          }
        }
      }
      __syncthreads();
    }
  }
}

template<int NTOT, int NTH>
__device__ void bitonic_merge_sh(float* v, int* id) {
  const int t = threadIdx.x;
  for (int j = NTOT >> 1; j > 0; j >>= 1) {
    for (int s = t; s < NTOT; s += NTH) {
      int p = s ^ j;
      if (p > s) {
        float v1 = v[s], v2 = v[p];
        int i1 = id[s], i2 = id[p];
        if (before_(v2, i2, v1, i1)) {
          v[s] = v2; id[s] = i2; v[p] = v1; id[p] = i1;
        }
      }
    }
    __syncthreads();
  }
}

// ---------------------------------------------------------------- fused preprocessing ----
// blk [0,11520): f2b3 segments (fc2_w, bb_w, rpn_w, head-pack)
// blk [11520,11912): im2col backbone (bf16 out)
// blk [11912,20104): fc1_w permute -> W1p [p][n][c] bf16
__global__ __launch_bounds__(256) void k_pre(
    const float* __restrict__ fc2_w, unsigned short* __restrict__ w2b,
    const float* __restrict__ bb_w, unsigned short* __restrict__ w0b,
    const float* __restrict__ rpn_w, unsigned short* __restrict__ w3b,
    const float* __restrict__ cw, const float* __restrict__ bw,
    unsigned short* __restrict__ hwb,
    const float* __restrict__ images, unsigned short* __restrict__ patch,
    const float* __restrict__ fc1_w, unsigned short* __restrict__ w1p)
{
  __shared__ unsigned short tile[128 * 50];
  int blk = blockIdx.x;
  const int t = threadIdx.x;
  if (blk < 11520) {
    int i = (blk * 256 + t) * 4;
    const float* s; unsigned short* d; int off;
    if (i < 1048576) { s = fc2_w; d = w2b; off = i; }
    else if (i < 2097152) { s = bb_w; d = w0b; off = i - 1048576; }
    else if (i < 11534336) { s = rpn_w; d = w3b; off = i - 2097152; }
    else {
      int off4 = i - 11534336;              // [0, 262144)
      int row = off4 >> 10, col = off4 & 1023;
      ushort4 o;
      if (row < 37) {
        float4 v = *(const float4*)(cw + (size_t)row * 1024 + col);
        o.x = f2b(v.x); o.y = f2b(v.y); o.z = f2b(v.z); o.w = f2b(v.w);
      } else if (row < 185) {
        float4 v = *(const float4*)(bw + (size_t)(row - 37) * 1024 + col);
        o.x = f2b(v.x); o.y = f2b(v.y); o.z = f2b(v.z); o.w = f2b(v.w);
      } else {
        o.x = 0; o.y = 0; o.z = 0; o.w = 0;
      }
      *(ushort4*)(hwb + off4) = o;
      return;
    }
    float4 v = *(const float4*)(s + off);
    ushort4 o;
    o.x = f2b(v.x); o.y = f2b(v.y); o.z = f2b(v.z); o.w = f2b(v.w);
    *(ushort4*)(d + off) = o;
    return;
  }
  blk -= 11520;
  if (blk < 392) {
    int i = blk * 256 + t;
    if (i >= 98 * 1024) return;
    int rowi = i >> 10, k = i & 1023;
    int b = rowi / 49, pos = rowi % 49;
    int oy = pos / 7, ox = pos % 7;
    int ky = k >> 5, kx = k & 31;
    patch[i] = f2b(images[((size_t)b * 224 + oy * 32 + ky) * 224 + ox * 32 + kx]);
    return;
  }
  blk -= 392;
  // w1perm2: n = blk/8, ct = blk%8
  {
    const int n = blk >> 3, ct = blk & 7;
    const float* src = fc1_w + (size_t)n * 50176 + (size_t)ct * 128 * 49;
    for (int i = t; i < 6272; i += 256) {
      int cl = i / 49, p = i % 49;
      tile[cl * 50 + p] = f2b(src[i]);
    }
    __syncthreads();
    for (int j = t; j < 6272; j += 256) {
      int p = j >> 7, cl = j & 127;
      w1p[((size_t)p * 1024 + n) * 1024 + (size_t)ct * 128 + cl] = tile[cl * 50 + p];
    }
  }
}

// ---------------------------------------------------------------- bf16 MFMA GEMM ----
// 1-deep pipeline, named prefetch regs, ONE barrier per K-step, XCD-grouped swizzle.
// Msplit>0: M is laid out as [2][Msplit] rows (one image per 768-row half);
// gating is local_m < nvalid[img] and B is offset by img*boff.
__global__ __launch_bounds__(256) void k_gemm_bf16(
    const unsigned short* __restrict__ A, int lda, int M,
    const unsigned short* __restrict__ B, int ldb,
    float* __restrict__ P, int N, int Kchunk,
    const int* __restrict__ nvalid, int Msplit, int boff)
{
  __shared__ __attribute__((aligned(16))) unsigned short As[2][128][40]; // 32 data + 8 pad
  __shared__ __attribute__((aligned(16))) unsigned short Bs[2][128][40];
  const int G = gridDim.x * gridDim.y * gridDim.z;
  int lid = blockIdx.x + gridDim.x * (blockIdx.y + gridDim.y * blockIdx.z);
  lid = (lid & 7) * (G >> 3) + (lid >> 3);
  const int bx = lid % gridDim.x;
  const int rest = lid / gridDim.x;
  const int by = rest % gridDim.y, bz = rest / gridDim.y;
  const int m0 = bx * 128, n0 = by * 128;
  if (nvalid) {
    int img = (Msplit && m0 >= Msplit) ? 1 : 0;
    int lm = m0 - img * Msplit;
    if (lm >= nvalid[img]) return;
    B += (size_t)img * boff;
  }
  const int t = threadIdx.x;
  const int lane = t & 63, wid = t >> 6;
  const int wm = (wid >> 1) * 64, wn = (wid & 1) * 64;
  const size_t k0 = (size_t)bz * Kchunk;
  f32x4 acc[4][4];
#pragma unroll
  for (int i = 0; i < 4; ++i)
#pragma unroll
    for (int j = 0; j < 4; ++j) acc[i][j] = (f32x4){0.f, 0.f, 0.f, 0.f};
  const int r0 = t >> 2, c0 = (t & 3) * 8;
  const int fr = lane & 15, fk = (lane >> 4) * 8;
  const int gmA0 = m0 + r0, gmA1 = m0 + r0 + 64;
  const bool vA0 = gmA0 < M, vA1 = gmA1 < M;
  const unsigned short* pA0 = A + (size_t)gmA0 * lda + k0 + c0;
  const unsigned short* pA1 = A + (size_t)gmA1 * lda + k0 + c0;
  const unsigned short* pB0 = B + (size_t)(n0 + r0) * ldb + k0 + c0;
  const unsigned short* pB1 = B + (size_t)(n0 + r0 + 64) * ldb + k0 + c0;
  bf16x8 rA0 = {}, rA1 = {}, rB0, rB1;
  if (vA0) rA0 = *(const bf16x8*)pA0;
  if (vA1) rA1 = *(const bf16x8*)pA1;
  rB0 = *(const bf16x8*)pB0;
  rB1 = *(const bf16x8*)pB1;
  const int nt = Kchunk >> 5;
  int cur = 0;
  for (int it = 0; it < nt; ++it) {
    *(bf16x8*)&As[cur][r0][c0] = rA0;
    *(bf16x8*)&As[cur][r0 + 64][c0] = rA1;
    *(bf16x8*)&Bs[cur][r0][c0] = rB0;
    *(bf16x8*)&Bs[cur][r0 + 64][c0] = rB1;
    __syncthreads();
    if (it + 1 < nt) {
      size_t ofs = (size_t)(it + 1) * 32;
      rA0 = vA0 ? *(const bf16x8*)(pA0 + ofs) : (bf16x8){};
      rA1 = vA1 ? *(const bf16x8*)(pA1 + ofs) : (bf16x8){};
      rB0 = *(const bf16x8*)(pB0 + ofs);
      rB1 = *(const bf16x8*)(pB1 + ofs);
    }
    bf16x8 af[4], bg[4];
#pragma unroll
    for (int i = 0; i < 4; ++i) af[i] = *(const bf16x8*)&As[cur][wm + i * 16 + fr][fk];
#pragma unroll
    for (int j = 0; j < 4; ++j) bg[j] = *(const bf16x8*)&Bs[cur][wn + j * 16 + fr][fk];
#pragma unroll
    for (int i = 0; i < 4; ++i)
#pragma unroll
      for (int j = 0; j < 4; ++j)
        acc[i][j] = __builtin_amdgcn_mfma_f32_16x16x32_bf16(af[i], bg[j], acc[i][j], 0, 0, 0);
    cur ^= 1;
  }
  // epilogue: C/D layout col=lane&15, row=(lane>>4)*4+reg  [m89/m91 verified]
  float* Pp = P + (size_t)bz * M * N;
#pragma unroll
  for (int i = 0; i < 4; ++i) {
#pragma unroll
    for (int r = 0; r < 4; ++r) {
      int gm = m0 + wm + i * 16 + (lane >> 4) * 4 + r;
      if (gm < M) {
#pragma unroll
        for (int j = 0; j < 4; ++j)
          Pp[(size_t)gm * N + n0 + wn + j * 16 + (lane & 15)] = acc[i][j][r];
      }
    }
  }
}

// ---------------------------------------------------------------- im2col_rpn + M-GEMM (fused) ----
// blk [0,3528): im2col for RPN 3x3 conv (reads bbh).
// blk [3528,3920): M-GEMM writing Bmat transposed (identical to prior k_gemm_mb, G=392).
__global__ __launch_bounds__(256) void k_imrpn_mb(
    const unsigned short* __restrict__ bbh,
    unsigned short* __restrict__ im2,
    const unsigned short* __restrict__ W1p,
    unsigned short* __restrict__ Bmat)
{
  __shared__ __attribute__((aligned(16))) unsigned short As[2][128][40];
  __shared__ __attribute__((aligned(16))) unsigned short Bs[2][128][40];
  __shared__ unsigned short tile[98][130];
  const int t = threadIdx.x;
  int blk = blockIdx.x;
  if (blk < 3528) {
    int i = blk * 256 + t;
    if (i >= 98 * 9216) return;
    int rowi = i / 9216, k = i % 9216;
    int b = rowi / 49, pos = rowi % 49;
    int oy = pos / 7, ox = pos % 7;
    int ic = k / 9, kk = k % 9;
    int ky = kk / 3, kx = kk % 3;
    int y = oy + ky - 1, x = ox + kx - 1;
    unsigned short v = 0;
    if ((unsigned)y < 7u && (unsigned)x < 7u)
      v = bbh[((size_t)(b * 49 + y * 7 + x)) * 1024 + ic];
    im2[i] = v;
    return;
  }
  int lid = blk - 3528;                       // [0,392)
  lid = (lid & 7) * 49 + (lid >> 3);          // XCD swizzle, G=392
  const int by = lid % 8, p = lid / 8;
  const int n0 = by * 128;
  const int M = 98;
  const unsigned short* B = W1p + (size_t)p * 1048576;
  const int lane = t & 63, wid = t >> 6;
  const int wm = (wid >> 1) * 64, wn = (wid & 1) * 64;
  f32x4 acc[4][4];
#pragma unroll
  for (int i = 0; i < 4; ++i)
#pragma unroll
    for (int j = 0; j < 4; ++j) acc[i][j] = (f32x4){0.f, 0.f, 0.f, 0.f};
  const int r0 = t >> 2, c0 = (t & 3) * 8;
  const int fr = lane & 15, fk = (lane >> 4) * 8;
  int gA0 = r0; if (gA0 >= M) gA0 = M - 1;
  int gA1 = r0 + 64; if (gA1 >= M) gA1 = M - 1;
  const unsigned short* pA0 = bbh + (size_t)gA0 * 1024 + c0;
  const unsigned short* pA1 = bbh + (size_t)gA1 * 1024 + c0;
  const unsigned short* pB0 = B + (size_t)(n0 + r0) * 1024 + c0;
  const unsigned short* pB1 = B + (size_t)(n0 + r0 + 64) * 1024 + c0;
  bf16x8 rA0 = *(const bf16x8*)pA0;
  bf16x8 rA1 = *(const bf16x8*)pA1;
  bf16x8 rB0 = *(const bf16x8*)pB0;
  bf16x8 rB1 = *(const bf16x8*)pB1;
  const int nt = 1024 >> 5;
  int cur = 0;
  for (int it = 0; it < nt; ++it) {
    *(bf16x8*)&As[cur][r0][c0] = rA0;
    *(bf16x8*)&As[cur][r0 + 64][c0] = rA1;
    *(bf16x8*)&Bs[cur][r0][c0] = rB0;
    *(bf16x8*)&Bs[cur][r0 + 64][c0] = rB1;
    __syncthreads();
    if (it + 1 < nt) {
      size_t ofs = (size_t)(it + 1) * 32;
      rA0 = *(const bf16x8*)(pA0 + ofs);
      rA1 = *(const bf16x8*)(pA1 + ofs);
      rB0 = *(const bf16x8*)(pB0 + ofs);
      rB1 = *(const bf16x8*)(pB1 + ofs);
    }
    bf16x8 af[4], bg[4];
#pragma unroll
    for (int i = 0; i < 4; ++i) af[i] = *(const bf16x8*)&As[cur][wm + i * 16 + fr][fk];
#pragma unroll
    for (int j = 0; j < 4; ++j) bg[j] = *(const bf16x8*)&Bs[cur][wn + j * 16 + fr][fk];
#pragma unroll
    for (int i = 0; i < 4; ++i)
#pragma unroll
      for (int j = 0; j < 4; ++j)
        acc[i][j] = __builtin_amdgcn_mfma_f32_16x16x32_bf16(af[i], bg[j], acc[i][j], 0, 0, 0);
    cur ^= 1;
  }
  __syncthreads();
#pragma unroll
  for (int i = 0; i < 4; ++i) {
#pragma unroll
    for (int r = 0; r < 4; ++r) {
      int gm = wm + i * 16 + (lane >> 4) * 4 + r;
      if (gm < M) {
#pragma unroll
        for (int j = 0; j < 4; ++j)
          tile[gm][wn + j * 16 + (lane & 15)] = f2b(acc[i][j][r]);
      }
    }
  }
  __syncthreads();
  {
    int nl = t >> 1, b2 = t & 1;
    unsigned short* dst = Bmat + (size_t)(n0 + nl) * KF1 + b2 * KHALF + p * 49;
    for (int qq = 0; qq < 49; ++qq) dst[qq] = tile[b2 * 49 + qq][nl];
  }
  if (p == 0) {  // zero pad cols 2401..2431 in each half (avoid garbage in MFMA)
    for (int j2 = t; j2 < 128 * 62; j2 += 256) {
      int nl = j2 / 62, e = j2 % 62;
      int bb = e >= 31 ? 1 : 0;
      int col = bb * KHALF + 2401 + (e - bb * 31);
      Bmat[(size_t)(n0 + nl) * KF1 + col] = 0;
    }
  }
}

// ---------------------------------------------------------------- G build ----
// Gmat rows laid out [2][768]; row rg = b*768+r holds only its image's K-half.
__global__ __launch_bounds__(256) void k_gbuild(const float* __restrict__ props,
                                                unsigned short* __restrict__ Gmat)
{
#pragma clang fp contract(off)
  int rg = blockIdx.x;
  int b = rg / MROW, r = rg % MROW;
  __shared__ float g[KHALF];
  int t = threadIdx.x;
  for (int j = t; j < KHALF; j += 256) g[j] = 0.f;
  __syncthreads();
  if (t < 49) {
    int pr = b * NANCH + r; if (pr > 2 * NANCH - 1) pr = 2 * NANCH - 1;
    const float* roi = props + (size_t)pr * 4;
    int p = t, oy = p / 7, ox = p % 7;
    float x1 = roi[0] * 0.03125f, y1 = roi[1] * 0.03125f;
    float rw = fmaxf(roi[2] * 0.03125f - x1, 1.f);
    float rh = fmaxf(roi[3] * 0.03125f - y1, 1.f);
    float bw = rw / 7.f, bh = rh / 7.f;
    float* gb = g + p * 49;
    for (int iy = 0; iy < 2; ++iy) {
      for (int ix = 0; ix < 2; ++ix) {
        float ys = y1 + ((float)oy + ((float)iy + 0.5f) * 0.5f) * bh;
        float xs = x1 + ((float)ox + ((float)ix + 0.5f) * 0.5f) * bw;
        bool vy = (ys >= -1.f) && (ys <= 7.f);
        bool vx = (xs >= -1.f) && (xs <= 7.f);
        float yc = fmaxf(ys, 0.f), xc = fmaxf(xs, 0.f);
        int y0 = min(max((int)floorf(yc), 0), 6), x0 = min(max((int)floorf(xc), 0), 6);
        int y1i = min(y0 + 1, 6), x1i = min(x0 + 1, 6);
        if (y0 == 6) yc = 6.f;
        if (x0 == 6) xc = 6.f;
        float ly = yc - (float)y0, lx = xc - (float)x0;
        float hy = 1.f - ly, hx = 1.f - lx;
        float vm = (vy && vx) ? 0.25f : 0.f;
        gb[y0 * 7 + x0]   += hy * hx * vm;
        gb[y0 * 7 + x1i]  += hy * lx * vm;
        gb[y1i * 7 + x0]  += ly * hx * vm;
        gb[y1i * 7 + x1i] += ly * lx * vm;
      }
    }
  }
  __syncthreads();
  unsigned short* Gr = Gmat + (size_t)rg * KHALF;
  for (int j = t; j < KHALF; j += 256) Gr[j] = f2b(g[j]);
}

// flags: 1=overwrite(dst ignored), 2=add bias, 4=relu, 8=write bf16 to dst16,
//        16=skip fp32 dst write
__global__ void k_reduce(const float* __restrict__ P, float* __restrict__ dst,
                         unsigned short* __restrict__ dst16,
                         int S, int M, int N, const float* __restrict__ bias, int flags)
{
  size_t i = (size_t)blockIdx.x * 256 + threadIdx.x;
  size_t tot = (size_t)M * N;
  if (i >= tot) return;
  float v = (flags & 1) ? 0.f : dst[i];
  for (int s = 0; s < S; ++s) v += P[(size_t)s * tot + i];
  if (flags & 2) v += bias[i % (size_t)N];
  if (flags & 4) v = fmaxf(v, 0.f);
  if (!(flags & 16)) dst[i] = v;
  if (flags & 8) dst16[i] = f2b(v);
}

// ---------------------------------------------------------------- RPN heads ----
__global__ __launch_bounds__(256) void k_rpn_head(
    const float* __restrict__ tmn, const float* __restrict__ cls_w,
    const float* __restrict__ cls_b, const float* __restrict__ reg_w,
    const float* __restrict__ reg_b, float* __restrict__ obj, float* __restrict__ reg)
{
  int blk = blockIdx.x;
  __shared__ float col[1024];
  const float* row = tmn + (size_t)blk * 1024;
  for (int i = threadIdx.x; i < 1024; i += 256) col[i] = row[i];
  __syncthreads();
  int b = blk / 49, pos = blk % 49;
  for (int o = threadIdx.x; o < 75; o += 256) {
    const float* w = (o < 15) ? (cls_w + (size_t)o * 1024) : (reg_w + (size_t)(o - 15) * 1024);
    float s = 0.f;
    for (int k = 0; k < 1024; ++k) s = fmaf(col[k], w[k], s);
    if (o < 15) {
      obj[(size_t)b * NANCH + pos * 15 + o] = s + cls_b[o];
    } else {
      int c = o - 15, a = c >> 2, d = c & 3;
      reg[((size_t)b * NANCH + pos * 15 + a) * 4 + d] = s + reg_b[c];
    }
  }
}

// ---------------------------------------------------------------- RPN stage 1 ----
__global__ __launch_bounds__(1024) void k_rpn_prep(
    const float* __restrict__ obj, const float* __restrict__ reg,
    float* __restrict__ bxp, float* __restrict__ pnms)
{
#pragma clang fp contract(off)
  const int b = blockIdx.x, t = threadIdx.x;
  __shared__ float sval[1024];
  __shared__ float vo1[1024];
  __shared__ int o1a[1024];
  __shared__ int wtv[16];
  __shared__ int wti[16];
  sval[t] = (t < NANCH) ? obj[(size_t)b * NANCH + t] : -INFINITY;
  __syncthreads();
  {
    float v = sval[t];
    int rank = 0;
    for (int j = 0; j < NANCH; ++j) {
      float u = sval[j];
      rank += (u > v) || (u == v && j < t);
    }
    if (t < NANCH) { vo1[rank] = v; o1a[rank] = t; }
  }
  __syncthreads();
  float x1 = 0.f, y1 = 0.f, x2 = 0.f, y2 = 0.f, prob = -1.f;
  bool flag = false;
  if (t < NANCH) {
    int ai = o1a[t];
    const float* d = reg + ((size_t)b * NANCH + ai) * 4;
    float an[4];
    anchor_of(ai, an);
    float aw = an[2] - an[0], ah = an[3] - an[1];
    float acx = an[0] + 0.5f * aw, acy = an[1] + 0.5f * ah;
    float dw = fminf(d[2], BBCLIP), dh = fminf(d[3], BBCLIP);
    float pcx = d[0] * aw + acx, pcy = d[1] * ah + acy;
    float pw = expf(dw) * aw, ph = expf(dh) * ah;
    x1 = pcx - 0.5f * pw; y1 = pcy - 0.5f * ph;
    x2 = pcx + 0.5f * pw; y2 = pcy + 0.5f * ph;
    x1 = fminf(fmaxf(x1, 0.f), 224.f);
    y1 = fminf(fmaxf(y1, 0.f), 224.f);
    x2 = fminf(fmaxf(x2, 0.f), 224.f);
    y2 = fminf(fmaxf(y2, 0.f), 224.f);
    flag = (x2 - x1 >= 1e-3f) && (y2 - y1 >= 1e-3f);
    prob = 1.f / (1.f + expf(-vo1[t]));
  }
  bool iflag = (t < NANCH) && !flag;
  unsigned long long balv = __ballot(flag);
  unsigned long long bali = __ballot(iflag);
  int lane = t & 63, w = t >> 6;
  if (lane == 0) { wtv[w] = __popcll(balv); wti[w] = __popcll(bali); }
  __syncthreads();
  int nval = 0, basev = 0, basei = 0;
  for (int k = 0; k < 16; ++k) {
    int cv = wtv[k], ci = wti[k];
    nval += cv;
    if (k < w) { basev += cv; basei += ci; }
  }
  if (t < NANCH) {
    unsigned long long lm = (1ull << lane) - 1;
    int pos = flag ? (basev + __popcll(balv & lm))
                   : (nval + basei + __popcll(bali & lm));
    float* o = bxp + ((size_t)b * NANCH + pos) * 4;
    o[0] = x1; o[1] = y1; o[2] = x2; o[3] = y2;
    pnms[(size_t)b * NANCH + pos] = flag ? prob : -1.f;
  }
}

// ---------------------------------------------------------------- RPN stage 2 ----
__global__ __launch_bounds__(256) void k_rpn_mask(
    const float* __restrict__ bxp, unsigned long long* __restrict__ rmask)
{
#pragma clang fp contract(off)
  int blk = blockIdx.x;
  int b = blk / 35;
  int row = (blk % 35) * 21 + (int)(threadIdx.x / 12);
  int w = threadIdx.x % 12;
  if (threadIdx.x >= 252 || row >= NANCH) return;
  const float* a = bxp + ((size_t)b * NANCH + row) * 4;
  float a0 = a[0], a1 = a[1], a2 = a[2], a3 = a[3];
  float aarea = (a2 - a0) * (a3 - a1);
  int l0 = w * 64;
  int l1 = (l0 + 64 < NANCH) ? l0 + 64 : NANCH;
  int ls = (l0 > row + 1) ? l0 : row + 1;
  unsigned long long bits = 0ull;
  for (int l = ls; l < l1; ++l) {
    const float* q = bxp + ((size_t)b * NANCH + l) * 4;
    float b0 = q[0], b1 = q[1], b2 = q[2], b3 = q[3];
    float barea = (b2 - b0) * (b3 - b1);
    float ix1 = fmaxf(a0, b0), iy1 = fmaxf(a1, b1);
    float ix2 = fminf(a2, b2), iy2 = fminf(a3, b3);
    float iw = fmaxf(ix2 - ix1, 0.f), ih = fmaxf(iy2 - iy1, 0.f);
    float inter = iw * ih;
    float iou = inter / fmaxf(aarea + barea - inter, 1e-9f);
    if (iou > 0.7f) bits |= 1ull << (l & 63);
  }
  rmask[((size_t)b * NANCH + row) * 12 + w] = bits;
}

// ---------------------------------------------------------------- RPN stage 3 ----
__global__ __launch_bounds__(1024) void k_rpn_fin(
    const float* __restrict__ bxp, const float* __restrict__ pnms,
    const unsigned long long* __restrict__ rmask,
    float* __restrict__ props, int* __restrict__ meta)
{
  const int b = blockIdx.x, t = threadIdx.x;
  __shared__ unsigned long long smask[NANCH * 12];
  __shared__ float sp[1024];
  __shared__ unsigned long long keepw[12];
  __shared__ int wtot[16];
  for (int i = t; i < NANCH * 12; i += 1024)
    smask[i] = rmask[(size_t)b * NANCH * 12 + i];
  sp[t] = (t < NANCH) ? pnms[(size_t)b * NANCH + t] : -1.f;
  __syncthreads();
  if (t < 64) {
    unsigned long long kl = (t < 12) ? ~0ull : 0ull;
    for (int i = 0; i < NANCH; ++i) {
      unsigned long long kw = __shfl(kl, i >> 6);
      unsigned long long m = (t < 12) ? smask[i * 12 + t] : 0ull;
      bool on = (kw >> (i & 63)) & 1ull;
      kl &= on ? ~m : ~0ull;
    }
    if (t < 12) keepw[t] = kl;
  }
  __syncthreads();
  bool flag = false;
  if (t < NANCH) {
    bool kp = (keepw[t >> 6] >> (t & 63)) & 1ull;
    flag = kp && (sp[t] > 0.f);
  }
  unsigned long long bal = __ballot(flag);
  int lane = t & 63, w = t >> 6;
  if (lane == 0) wtot[w] = __popcll(bal);
  __syncthreads();
  int base = 0, tot = 0;
  for (int k = 0; k < 16; ++k) { int c = wtot[k]; if (k < w) base += c; tot += c; }
  if (flag) {
    int pos = base + __popcll(bal & ((1ull << lane) - 1));
    const float* src = bxp + ((size_t)b * NANCH + t) * 4;
    float* o = props + ((size_t)b * NANCH + pos) * 4;
    o[0] = src[0]; o[1] = src[1]; o[2] = src[2]; o[3] = src[3];
  }
  if (t == 0) meta[b] = tot;
}

// ---------------------------------------------------------------- candidates (from head GEMM P) ----
// P layout: [z][MTOT][256] fp32 (rows = b*768+r); cols 0..36 logits, 37..184 deltas.
__global__ void k_cand(const float* __restrict__ P, const float* __restrict__ cb_,
                       const float* __restrict__ bb_, const float* __restrict__ props,
                       const int* __restrict__ meta,
                       float* __restrict__ cscore, float* __restrict__ cbox)
{
#pragma clang fp contract(off)
  int rg = blockIdx.x * blockDim.x + threadIdx.x;
  if (rg >= 2 * NANCH) return;
  int b = rg / NANCH, r = rg % NANCH;
  float* cs = cscore + (size_t)b * NCANDP;
  float* cbx = cbox + (size_t)b * NCANDP * 4;
  int base = r * 36;
  if (r >= meta[b]) {
    for (int j = 0; j < 36; ++j) {
      cs[base + j] = -1.f;
      float* q = cbx + (size_t)(base + j) * 4;
      q[0] = 0.f; q[1] = 0.f; q[2] = 0.f; q[3] = 0.f;
    }
    return;
  }
  int row = b * MROW + r;
  const float* p0 = P + (size_t)row * 256;
  const float* p1 = P + (size_t)MTOT * 256 + (size_t)row * 256;
  float lg[37];
  for (int c = 0; c < 37; ++c) lg[c] = p0[c] + p1[c] + cb_[c];
  float mx = lg[0];
  for (int c = 1; c < 37; ++c) mx = fmaxf(mx, lg[c]);
  float sum = 0.f;
  for (int c = 0; c < 37; ++c) sum += expf(lg[c] - mx);
  const float* roi = props + (size_t)rg * 4;
  float rw = roi[2] - roi[0], rh = roi[3] - roi[1];
  float rcx = roi[0] + 0.5f * rw, rcy = roi[1] + 0.5f * rh;
  for (int c = 1; c < 37; ++c) {
    float d0 = p0[37 + c * 4]     + p1[37 + c * 4]     + bb_[c * 4];
    float d1 = p0[37 + c * 4 + 1] + p1[37 + c * 4 + 1] + bb_[c * 4 + 1];
    float d2 = p0[37 + c * 4 + 2] + p1[37 + c * 4 + 2] + bb_[c * 4 + 2];
    float d3 = p0[37 + c * 4 + 3] + p1[37 + c * 4 + 3] + bb_[c * 4 + 3];
    float dx = d0 / 10.f, dy = d1 / 10.f;
    float dw = fminf(d2 / 5.f, BBCLIP), dh = fminf(d3 / 5.f, BBCLIP);
    float pcx = dx * rw + rcx, pcy = dy * rh + rcy;
    float pw = expf(dw) * rw, ph = expf(dh) * rh;
    float x1 = pcx - 0.5f * pw, y1 = pcy - 0.5f * ph;
    float x2 = pcx + 0.5f * pw, y2 = pcy + 0.5f * ph;
    x1 = fminf(fmaxf(x1, 0.f), 224.f);
    y1 = fminf(fmaxf(y1, 0.f), 224.f);
    x2 = fminf(fmaxf(x2, 0.f), 224.f);
    y2 = fminf(fmaxf(y2, 0.f), 224.f);
    float sc = expf(lg[c] - mx) / sum;
    bool ok = ((x2 - x1) >= 1e-2f) && ((y2 - y1) >= 1e-2f) && (sc > 0.05f);
    cs[base + c - 1] = ok ? sc : -1.f;
    float* q = cbx + (size_t)(base + c - 1) * 4;
    q[0] = x1; q[1] = y1; q[2] = x2; q[3] = y2;
  }
}

// ---------------------------------------------------------------- top 2048 ----
__global__ __launch_bounds__(1024) void k_top2048(
    const float* __restrict__ cscore,
    float* __restrict__ sel_score, int* __restrict__ sel_cidx,
    int* __restrict__ meta)
{
  const int b = blockIdx.x, t = threadIdx.x;
  __shared__ float Lv[2048]; __shared__ int Li[2048];
  __shared__ float Cv[2048]; __shared__ int Ci[2048];
  __shared__ int cnt;
  const float* cs = cscore + (size_t)b * NCANDP;
  if (t == 0) cnt = 0;
  __syncthreads();
  for (int gi = t; gi < NCAND; gi += 1024) {
    float v = cs[gi];
    if (v > 0.f) {
      int p = atomicAdd(&cnt, 1);
      if (p < 2048) { Cv[p] = v; Ci[p] = gi; }
    }
  }
  __syncthreads();
  int npos = cnt;
  if (npos <= 2048) {
    for (int h = 0; h < 2; ++h) {
      int p = h * 1024 + t;
      if (p < npos) {
        float v = Cv[p]; int id = Ci[p];
        int rank = 0;
        for (int j = 0; j < npos; ++j) {
          float u = Cv[j]; int ju = Ci[j];
          rank += (u > v) || (u == v && ju < id);
        }
        sel_score[b * 2048 + rank] = v;
        sel_cidx[b * 2048 + rank] = id;
      }
      if (p >= npos && p < 2048) {
        sel_score[b * 2048 + p] = -1.f;
        sel_cidx[b * 2048 + p] = 0;
      }
    }
    if (t == 0) meta[2 + b] = npos;
    return;
  }
  for (int chunk = 0; chunk < 13; ++chunk) {
    for (int s = t; s < 2048; s += 1024) {
      int gi = chunk * 2048 + s;
      Cv[s] = (gi < NCAND) ? cs[gi] : -INFINITY;
      Ci[s] = gi;
    }
    __syncthreads();
    bitonic_sort_sh<2048, 1024>(Cv, Ci);
    if (chunk == 0) {
      for (int s = t; s < 2048; s += 1024) { Lv[s] = Cv[s]; Li[s] = Ci[s]; }
      __syncthreads();
    } else {
      for (int s = t; s < 2048; s += 1024) {
        float cv = Cv[2047 - s]; int ci = Ci[2047 - s];
        if (before_(cv, ci, Lv[s], Li[s])) { Lv[s] = cv; Li[s] = ci; }
      }
      __syncthreads();
      bitonic_merge_sh<2048, 1024>(Lv, Li);
    }
  }
  for (int s = t; s < 2048; s += 1024) {
    sel_score[b * 2048 + s] = Lv[s];
    sel_cidx[b * 2048 + s] = Li[s];
  }
  if (t == 0) meta[2 + b] = 2048;
}

// ---------------------------------------------------------------- det NMS mask ----
__global__ void k_detmask(const int* __restrict__ sel_cidx,
                          const float* __restrict__ cbox,
                          const int* __restrict__ meta,
                          unsigned long long* __restrict__ dmask)
{
#pragma clang fp contract(off)
  int blk = blockIdx.x;
  int b = blk >> 8, row0 = (blk & 255) * 8;
  int npos = meta[2 + b];
  if (row0 >= npos) return;
  int t = threadIdx.x;
  int i = row0 + (t >> 5), w = t & 31;
  if (i >= npos) return;
  int ci = sel_cidx[b * 2048 + i];
  const float* bp = cbox + ((size_t)b * NCANDP + ci) * 4;
  float off = (float)(ci % 36 + 1) * 225.f;
  float a0 = bp[0] + off, a1 = bp[1] + off, a2 = bp[2] + off, a3 = bp[3] + off;
  float aarea = (a2 - a0) * (a3 - a1);
  unsigned long long bits = 0ull;
  int l0 = w * 64;
  int l1 = (l0 + 64 < npos) ? l0 + 64 : npos;
  int ls = (l0 > i + 1) ? l0 : i + 1;
  for (int l = ls; l < l1; ++l) {
    int cl = sel_cidx[b * 2048 + l];
    const float* q = cbox + ((size_t)b * NCANDP + cl) * 4;
    float o2 = (float)(cl % 36 + 1) * 225.f;
    float b0 = q[0] + o2, b1 = q[1] + o2, b2 = q[2] + o2, b3 = q[3] + o2;
    float barea = (b2 - b0) * (b3 - b1);
    float ix1 = fmaxf(a0, b0), iy1 = fmaxf(a1, b1);
    float ix2 = fminf(a2, b2), iy2 = fminf(a3, b3);
    float iw = fmaxf(ix2 - ix1, 0.f), ih = fmaxf(iy2 - iy1, 0.f);
    float inter = iw * ih;
    float iou = inter / fmaxf(aarea + barea - inter, 1e-9f);
    if (iou > 0.5f) bits |= 1ull << (l & 63);
  }
  dmask[((size_t)b * 2048 + i) * 32 + w] = bits;
}

// ---------------------------------------------------------------- final ----
__global__ __launch_bounds__(1024) void k_final(
    const float* __restrict__ sel_score, const int* __restrict__ sel_cidx,
    const float* __restrict__ cbox, const unsigned long long* __restrict__ dmask,
    const int* __restrict__ meta, float* __restrict__ out)
{
  const int b = blockIdx.x, t = threadIdx.x;
  __shared__ unsigned long long keepw[32];
  __shared__ float sv[2048];
  __shared__ float kv[2048]; __shared__ int ks[2048];
  __shared__ int wtot[32];
  int npos = meta[2 + b];
  for (int h = 0; h < 2; ++h) {
    int s = h * 1024 + t;
    sv[s] = sel_score[b * 2048 + s];
  }
  __syncthreads();
  if (t < 64) {
    unsigned long long kl = (t < 32) ? ~0ull : 0ull;
    for (int i = 0; i < npos; ++i) {
      unsigned long long kw = __shfl(kl, i >> 6);
      unsigned long long m = (t < 32) ? dmask[((size_t)b * 2048 + i) * 32 + t] : 0ull;
      bool on = (kw >> (i & 63)) & 1ull;
      kl &= on ? ~m : ~0ull;
    }
    if (t < 32) keepw[t] = kl;
  }
  __syncthreads();
  const int lane = t & 63, w = t >> 6;
  int s0 = t;
  bool f0 = ((keepw[s0 >> 6] >> (s0 & 63)) & 1ull) && (sv[s0] > 0.f);
  unsigned long long bal0 = __ballot(f0);
  if (lane == 0) wtot[w] = __popcll(bal0);
  int s1 = 1024 + t;
  bool f1 = ((keepw[s1 >> 6] >> (s1 & 63)) & 1ull) && (sv[s1] > 0.f);
  unsigned long long bal1 = __ballot(f1);
  if (lane == 0) wtot[16 + w] = __popcll(bal1);
  __syncthreads();
  int nk = 0, base0 = 0, base1 = 0;
  for (int k = 0; k < 32; ++k) {
    int c = wtot[k];
    if (k < w) base0 += c;
    if (k < 16 + w) base1 += c;
    nk += c;
  }
  int p0 = -1, p1 = -1;
  if (f0) { p0 = base0 + __popcll(bal0 & ((1ull << lane) - 1)); kv[p0] = sv[s0]; ks[p0] = s0; }
  if (f1) { p1 = base1 + __popcll(bal1 & ((1ull << lane) - 1)); kv[p1] = sv[s1]; ks[p1] = s1; }
  __syncthreads();
  if (f0) {
    float v = sv[s0]; int rank = 0;
    for (int j = 0; j < nk; ++j) { float u = kv[j]; int ju = ks[j]; rank += (u > v) || (u == v && ju < s0); }
    if (rank < 100) {
      int ci = sel_cidx[b * 2048 + s0];
      const float* bp = cbox + ((size_t)b * NCANDP + ci) * 4;
      float* o = out + ((size_t)b * 100 + rank) * 6;
      o[0] = bp[0]; o[1] = bp[1]; o[2] = bp[2]; o[3] = bp[3];
      o[4] = v; o[5] = (float)(ci % 36 + 1);
    }
  }
  if (f1) {
    float v = sv[s1]; int rank = 0;
    for (int j = 0; j < nk; ++j) { float u = kv[j]; int ju = ks[j]; rank += (u > v) || (u == v && ju < s1); }
    if (rank < 100) {
      int ci = sel_cidx[b * 2048 + s1];
      const float* bp = cbox + ((size_t)b * NCANDP + ci) * 4;
      float* o = out + ((size_t)b * 100 + rank) * 6;
      o[0] = bp[0]; o[1] = bp[1]; o[2] = bp[2]; o[3] = bp[3];
      o[4] = v; o[5] = (float)(ci % 36 + 1);
    }
  }
  if (t < 100 && t >= nk) {
    float* o = out + ((size_t)b * 100 + t) * 6;
    o[0] = 0.f; o[1] = 0.f; o[2] = 0.f; o[3] = 0.f; o[4] = 0.f; o[5] = 0.f;
  }
}

// ---------------------------------------------------------------- host ----
extern "C" void kernel_launch(void* const* d_in, const int* in_sizes, int n_in,
                              void* d_out, int out_size, void* d_ws, size_t ws_size,
                              hipStream_t stream)
{
  (void)in_sizes; (void)n_in; (void)out_size; (void)ws_size;
  const float* images = (const float*)d_in[0];
  const float* bb_w   = (const float*)d_in[1];
  const float* bb_b   = (const float*)d_in[2];
  const float* rpn_w  = (const float*)d_in[3];
  const float* rpn_b  = (const float*)d_in[4];
  const float* cls_w  = (const float*)d_in[5];
  const float* cls_b  = (const float*)d_in[6];
  const float* reg_w  = (const float*)d_in[7];
  const float* reg_b  = (const float*)d_in[8];
  const float* fc1_w  = (const float*)d_in[9];
  const float* fc1_b  = (const float*)d_in[10];
  const float* fc2_w  = (const float*)d_in[11];
  const float* fc2_b  = (const float*)d_in[12];
  const float* clsp_w = (const float*)d_in[13];
  const float* clsp_b = (const float*)d_in[14];
  const float* boxp_w = (const float*)d_in[15];
  const float* boxp_b = (const float*)d_in[16];
  float* out = (float*)d_out;
  char* ws = (char*)d_ws;

  size_t off = 0;
  auto alloc = [&](size_t bytes) -> size_t {
    size_t o = off; off = (off + bytes + 255) & ~(size_t)255; return o;
  };
  size_t o_patch = alloc(98ull * 1024 * 2);      // im2col backbone, bf16
  size_t o_bbC   = alloc(98ull * 1024 * 4);      // fp32 slot (unused data path, kept)
  size_t o_bbh   = alloc(98ull * 1024 * 2);      // F = feats bf16 (position-major)
  size_t o_t     = alloc(98ull * 1024 * 4);
  size_t o_im2   = alloc(98ull * 9216 * 2);      // im2col rpn, bf16
  size_t o_obj   = alloc(1470ull * 4);
  size_t o_reg   = alloc(1470ull * 16);
  size_t o_props = alloc(1470ull * 16);
  size_t o_bxp   = alloc(1470ull * 16);
  size_t o_pnms  = alloc(1470ull * 4);
  size_t o_rm    = alloc(1470ull * 12 * 8);
  size_t o_meta  = alloc(256);
  size_t o_y1    = alloc((size_t)MTOT * 1024 * 4);  // fp32 slot (unused data path)
  size_t o_cs    = alloc(2ull * NCANDP * 4);
  size_t o_cb    = alloc(2ull * NCANDP * 16);
  size_t o_ss    = alloc(2ull * 2048 * 4);
  size_t o_sc    = alloc(2ull * 2048 * 4);
  size_t o_dm    = alloc(2ull * 2048 * 32 * 8);
  size_t o_w0b   = alloc(1048576ull * 2);        // bb_w bf16
  size_t o_w3b   = alloc(9437184ull * 2);        // rpn_w bf16
  size_t o_w1p   = alloc(51380224ull * 2);       // W1p [49][1024][1024] bf16
  size_t o_bmat  = alloc(1024ull * KF1 * 2);     // Bmat [1024][4864] bf16
  size_t o_gmat  = alloc((size_t)MTOT * KHALF * 2); // Gmat [1536][2432] bf16
  size_t o_w2b   = alloc(1048576ull * 2);        // fc2_w bf16
  size_t o_hwb   = alloc(256ull * 1024 * 2);     // predictor heads packed bf16
  size_t o_y1b   = alloc((size_t)MTOT * 1024 * 2); // fc1 out bf16
  size_t o_y2b   = alloc((size_t)MTOT * 1024 * 2); // fc2 out bf16
  size_t o_P     = alloc(32ull * 98 * 1024 * 4 > 2ull * MTOT * 1024 * 4
                         ? 32ull * 98 * 1024 * 4 : 2ull * MTOT * 1024 * 4);

  unsigned short* patchb = (unsigned short*)(ws + o_patch);
  float* bbC   = (float*)(ws + o_bbC);
  unsigned short* bbh = (unsigned short*)(ws + o_bbh);
  float* tb    = (float*)(ws + o_t);
  unsigned short* im2b = (unsigned short*)(ws + o_im2);
  float* objb  = (float*)(ws + o_obj);
  float* regb  = (float*)(ws + o_reg);
  float* props = (float*)(ws + o_props);
  float* bxp   = (float*)(ws + o_bxp);
  float* pnms  = (float*)(ws + o_pnms);
  unsigned long long* rmb = (unsigned long long*)(ws + o_rm);
  int*   meta  = (int*)(ws + o_meta);
  float* y1    = (float*)(ws + o_y1);
  float* csb   = (float*)(ws + o_cs);
  float* cbb   = (float*)(ws + o_cb);
  float* ssb   = (float*)(ws + o_ss);
  int*   scb   = (int*)(ws + o_sc);
  unsigned long long* dmb = (unsigned long long*)(ws + o_dm);
  unsigned short* w0b = (unsigned short*)(ws + o_w0b);
  unsigned short* w3b = (unsigned short*)(ws + o_w3b);
  unsigned short* w1p = (unsigned short*)(ws + o_w1p);
  unsigned short* bmat = (unsigned short*)(ws + o_bmat);
  unsigned short* gmat = (unsigned short*)(ws + o_gmat);
  unsigned short* w2b = (unsigned short*)(ws + o_w2b);
  unsigned short* hwb = (unsigned short*)(ws + o_hwb);
  unsigned short* y1b = (unsigned short*)(ws + o_y1b);
  unsigned short* y2b = (unsigned short*)(ws + o_y2b);
  float* Pb    = (float*)(ws + o_P);

  // fused preprocessing: weight conversions + head pack + backbone im2col + fc1_w permute
  k_pre<<<20104, 256, 0, stream>>>(fc2_w, w2b, bb_w, w0b, rpn_w, w3b,
                                   clsp_w, boxp_w, hwb, images, patchb, fc1_w, w1p);
  // backbone conv as bf16 MFMA GEMM, z=8; bf16-only output (F = bbh)
  k_gemm_bf16<<<dim3(1, 8, 8), 256, 0, stream>>>(patchb, 1024, 98, w0b, 1024, Pb, 1024, 128, nullptr, 0, 0);
  k_reduce<<<392, 256, 0, stream>>>(Pb, bbC, bbh, 8, 98, 1024, bb_b, 31);
  // fused: RPN im2col + M-GEMM (Bmat direct)
  k_imrpn_mb<<<3920, 256, 0, stream>>>(bbh, im2b, w1p, bmat);
  // RPN 3x3 conv as bf16 MFMA GEMM, z=32
  k_gemm_bf16<<<dim3(1, 8, 32), 256, 0, stream>>>(im2b, 9216, 98, w3b, 9216, Pb, 1024, 288, nullptr, 0, 0);
  k_reduce<<<392, 256, 0, stream>>>(Pb, tb, nullptr, 32, 98, 1024, rpn_b, 7);
  // RPN 1x1 heads + proposal filtering (3-stage, CU-parallel IoU mask)
  k_rpn_head<<<98, 256, 0, stream>>>(tb, cls_w, cls_b, reg_w, reg_b, objb, regb);
  k_rpn_prep<<<2, 1024, 0, stream>>>(objb, regb, bxp, pnms);
  k_rpn_mask<<<70, 256, 0, stream>>>(bxp, rmb);
  k_rpn_fin<<<2, 1024, 0, stream>>>(bxp, pnms, rmb, props, meta);
  // RoIAlign-as-linear-op: G build ([1536][2432]), fc1 = G @ Bmat[img-half]^T (K=2432, z=2)
  k_gbuild<<<MTOT, 256, 0, stream>>>(props, gmat);
  k_gemm_bf16<<<dim3(12, 8, 2), 256, 0, stream>>>(gmat, KHALF, MTOT, bmat, KF1, Pb, 1024, 1216, meta, MROW, KHALF);
  k_reduce<<<6144, 256, 0, stream>>>(Pb, y1, y1b, 2, MTOT, 1024, fc1_b, 31);
  // fc2 via bf16 MFMA, z=2; bf16-only output
  k_gemm_bf16<<<dim3(12, 8, 2), 256, 0, stream>>>(y1b, 1024, MTOT, w2b, 1024, Pb, 1024, 512, meta, MROW, 0);
  k_reduce<<<6144, 256, 0, stream>>>(Pb, y1, y2b, 2, MTOT, 1024, fc2_b, 31);
  // predictor heads as bf16 MFMA GEMM (M=1536, N=256 packed, z=2), then candidates
  k_gemm_bf16<<<dim3(12, 2, 2), 256, 0, stream>>>(y2b, 1024, MTOT, hwb, 1024, Pb, 256, 512, meta, MROW, 0);
  k_cand<<<6, 256, 0, stream>>>(Pb, clsp_b, boxp_b, props, meta, csb, cbb);
  // top-2048, class-wise NMS, top-100
  k_top2048<<<2, 1024, 0, stream>>>(csb, ssb, scb, meta);
  k_detmask<<<512, 256, 0, stream>>>(scb, cbb, meta, dmb);
  k_final<<<2, 1024, 0, stream>>>(ssb, scb, cbb, dmb, meta, out);
}